// Round 2
// baseline (289.653 us; speedup 1.0000x reference)
//
#include <hip/hip_runtime.h>
#include <cstdint>
#include <cstddef>

// DigitCapsules routing: B=256, R=1152, C=10, IC=8, OC=16, 3 iters.
// R19: keep R18's u-elimination (recompute u from f16 W, L2-resident),
// but fix the pass structure: R18's pass was L2-LATENCY-bound (VALUBusy
// 20%, Occ 19%, 512 blocks, W re-loaded per r with no b-amortization).
// New pass = K1's proven tile layout: block (rc,bg) owns 16 r x 16 b,
// thread (c,rl,oq) holds its W f16 slice in 16 u32 REGS for the whole
// block, loops b through LDS f16 x. W logical traffic 755 -> 47 MB/pass.
// Softmax-over-c via one LDS logit round-trip per 8-b half (own logit
// kept in regs -> no dynamic index). Partials bf16 [b][72][80] (part1
// format), reduced by a generic reduce kernel (scale, vprev, nchunk)
// that also does the final squash.
//   L1 s1cvt: x.W f32 -> part1 bf16 [b][144][80]; emits wf16 (bg==0).
//   L2 reduce(part1,144,0.1,null  -> vsum1)
//   L3 pass(x,wf16,vsum1 -> partA [b][72][80])
//   L4 reduce(partA,72,1.0,vsum1 -> vsum2)       // v1 + squash(s2)
//   L5 pass(x,wf16,vsum2 -> partB)
//   L6 reduce(partB,72,1.0,null  -> out)         // squash(s3)
// Logits linear in v: b_t = u.(v1+..+v_{t-1}) -> running vsum (proven).
#define NB 256
#define NR 1152
#define NC 10
#define NI 8
#define NO 16
#define NRC 144      // r-chunks in s1cvt (8 r each)
#define NRC2 72      // r-chunks in pass (16 r each)

typedef _Float16 h2 __attribute__((ext_vector_type(2)));

#if defined(__has_builtin)
#if __has_builtin(__builtin_amdgcn_fdot2)
#define HAS_FDOT2 1
#endif
#if __has_builtin(__builtin_amdgcn_cvt_pkrtz)
#define HAS_PKRTZ 1
#endif
#endif

static __device__ __forceinline__ float fdot2(uint32_t a, uint32_t b, float c) {
#ifdef HAS_FDOT2
    return __builtin_amdgcn_fdot2(__builtin_bit_cast(h2, a),
                                  __builtin_bit_cast(h2, b), c, false);
#else
    const h2 av = __builtin_bit_cast(h2, a);
    const h2 bv = __builtin_bit_cast(h2, b);
    c = fmaf((float)av.x, (float)bv.x, c);
    return fmaf((float)av.y, (float)bv.y, c);
#endif
}

static __device__ __forceinline__ uint32_t pk_f16(float a, float b) {
#ifdef HAS_PKRTZ
    return __builtin_bit_cast(uint32_t, __builtin_amdgcn_cvt_pkrtz(a, b));
#else
    h2 v; v.x = (_Float16)a; v.y = (_Float16)b;
    return __builtin_bit_cast(uint32_t, v);
#endif
}

static __device__ __forceinline__ uint32_t bf16_pack2(float lo, float hi) {
    uint32_t vl = __float_as_uint(lo);
    vl = vl + 0x7FFFu + ((vl >> 16) & 1u);
    uint32_t vh = __float_as_uint(hi);
    vh = vh + 0x7FFFu + ((vh >> 16) & 1u);
    return (vl >> 16) | (vh & 0xFFFF0000u);
}

// -------------------------------------------------------------------------
// caps_s1cvt: 2304 blocks = 144 rc x 16 bg; 320 thr = c*32 + rl*4 + oq.
// W[r][c][i][oq*4..+3] = 8 float4 in regs; 16-deep b-loop; fused s1 partial
// via rl-shuffle-reduce -> packed bf16 part1 (uint2). No u store.
// Side output: wf16 [r][c][oq][od 0..3][ip 0..3] f16x2 (bg==0 blocks only).
__global__ __launch_bounds__(320) void caps_s1cvt_kernel(
    const float* __restrict__ x, const float* __restrict__ W,
    uint32_t* __restrict__ part1, uint32_t* __restrict__ wf16)
{
    const int t  = threadIdx.x;
    const int c  = t >> 5;             // 0..9
    const int rl = (t & 31) >> 2;      // 0..7
    const int oq = t & 3;              // 0..3
    const int rc = blockIdx.x >> 4;    // 0..143
    const int bg = blockIdx.x & 15;    // 0..15
    const int b0 = bg * 16;
    const int r  = rc * 8 + rl;

    __shared__ float xs[16][8][8];     // 4 KB

    if (t < 256) {                     // 256 float4 = x[b0..+16)[rc*8..+8)[8]
        const int bi = t >> 4, rem = t & 15;
        const int rr = rem >> 1, hf = rem & 1;
        *(float4*)&xs[bi][rr][hf * 4] =
            *(const float4*)(x + ((size_t)(b0 + bi) * NR + rc * 8 + rr) * 8 + hf * 4);
    }

    const float* wb = W + ((size_t)r * NC + c) * (NI * NO) + oq * 4;
    float4 wf[8];
#pragma unroll
    for (int i = 0; i < 8; ++i) wf[i] = *(const float4*)(wb + i * NO);

    if (bg == 0) {                     // W f16 conversion, once per element
        const float* wfl = (const float*)wf;   // wfl[i*4+od]
        uint32_t* dst = wf16 + (((size_t)r * NC + c) * 4 + oq) * 16;
#pragma unroll
        for (int od = 0; od < 4; ++od) {
            uint4 wq;
            wq.x = pk_f16(wfl[0 * 4 + od], wfl[1 * 4 + od]);
            wq.y = pk_f16(wfl[2 * 4 + od], wfl[3 * 4 + od]);
            wq.z = pk_f16(wfl[4 * 4 + od], wfl[5 * 4 + od]);
            wq.w = pk_f16(wfl[6 * 4 + od], wfl[7 * 4 + od]);
            *(uint4*)(dst + od * 4) = wq;
        }
    }

    __syncthreads();

#pragma unroll 2
    for (int bi = 0; bi < 16; ++bi) {
        const float4 xv4a = *(const float4*)&xs[bi][rl][0];
        const float4 xv4b = *(const float4*)&xs[bi][rl][4];
        const float xr[8] = {xv4a.x, xv4a.y, xv4a.z, xv4a.w,
                             xv4b.x, xv4b.y, xv4b.z, xv4b.w};
        float ax = 0.f, ay = 0.f, az = 0.f, aw = 0.f;
#pragma unroll
        for (int i = 0; i < 8; ++i) {
            const float xv = xr[i];
            ax = fmaf(xv, wf[i].x, ax); ay = fmaf(xv, wf[i].y, ay);
            az = fmaf(xv, wf[i].z, az); aw = fmaf(xv, wf[i].w, aw);
        }
        // fused s1 partial: reduce fp32 quad over rl (lane bits 2..4)
        float sx = ax, sy = ay, sz = az, sw = aw;
#pragma unroll
        for (int off = 4; off <= 16; off <<= 1) {
            sx += __shfl_xor(sx, off); sy += __shfl_xor(sy, off);
            sz += __shfl_xor(sz, off); sw += __shfl_xor(sw, off);
        }
        if ((t & 28) == 0) {   // rl == 0 lanes: one uint2 per (bi,c,oq)
            uint2 p;
            p.x = bf16_pack2(sx, sy);
            p.y = bf16_pack2(sz, sw);
            *(uint2*)(part1 + ((size_t)(b0 + bi) * NRC + rc) * 80
                      + c * 8 + oq * 2) = p;
        }
    }
}

// -------------------------------------------------------------------------
// caps_reduce: outv[b][160] = (vprev? vprev : 0) + squash(scale * sum over
// nchunk rc of bf16 part[b][rc][80]). grid 256 (b), 192 thr (160 active).
// Serves: s1 (scale=0.1), mid (vprev=vsum1), final (outv = d_out).
__global__ __launch_bounds__(192) void caps_reduce_kernel(
    const uint32_t* __restrict__ part, const float* __restrict__ vprev,
    float* __restrict__ outv, int nchunk, float scale)
{
    const int b = blockIdx.x;
    const int t = threadIdx.x;
    if (t >= 160) return;
    const uint32_t* p = part + (size_t)b * nchunk * 80 + (t >> 1);
    const bool hi = t & 1;
    float s0 = 0.f, s1 = 0.f, s2 = 0.f, s3 = 0.f;
    for (int g = 0; g < nchunk; g += 4) {
        const uint32_t w0 = p[(g + 0) * 80];
        const uint32_t w1 = p[(g + 1) * 80];
        const uint32_t w2 = p[(g + 2) * 80];
        const uint32_t w3 = p[(g + 3) * 80];
        s0 += hi ? __uint_as_float(w0 & 0xFFFF0000u) : __uint_as_float(w0 << 16);
        s1 += hi ? __uint_as_float(w1 & 0xFFFF0000u) : __uint_as_float(w1 << 16);
        s2 += hi ? __uint_as_float(w2 & 0xFFFF0000u) : __uint_as_float(w2 << 16);
        s3 += hi ? __uint_as_float(w3 & 0xFFFF0000u) : __uint_as_float(w3 << 16);
    }
    const float s = scale * ((s0 + s1) + (s2 + s3));
    float n2 = s * s;
    n2 += __shfl_xor(n2, 1);
    n2 += __shfl_xor(n2, 2);
    n2 += __shfl_xor(n2, 4);
    n2 += __shfl_xor(n2, 8);
    const float nrm = sqrtf(n2);
    float v = s * (n2 / (1.f + n2) / (nrm + 1e-8f));
    if (vprev != nullptr) v += vprev[(size_t)b * 160 + t];
    outv[(size_t)b * 160 + t] = v;
}

// -------------------------------------------------------------------------
// Routing pass (R19): 1152 blocks = 72 rc x 16 bg; 640 thr = c*64+rl*4+oq
// (c 0..9, rl 0..15, oq 0..3). Thread holds W f16 for its (r,c,oq) in 16
// u32 regs; x staged f16 in LDS; vss = running v in LDS. Two 8-b halves:
// loop1 computes u (16 fdot2) + logit (oq-shuffle) -> lgs LDS + own reg;
// loop2 reads the 10-c logit row, softmax, weighted acc, rl-shuffle
// reduce -> bf16 partial [b][72][80] (part1 format).
__global__ __launch_bounds__(640) void caps_pass_kernel(
    const float* __restrict__ x, const uint32_t* __restrict__ wf16,
    const float* __restrict__ vsum, uint32_t* __restrict__ part)
{
    const int t  = threadIdx.x;
    const int c  = t >> 6;            // 0..9
    const int rl = (t & 63) >> 2;     // 0..15
    const int oq = t & 3;             // 0..3
    const int rc = blockIdx.x >> 4;   // 0..71
    const int bg = blockIdx.x & 15;   // 0..15
    const int b0 = bg * 16;
    const int r  = rc * 16 + rl;

    __shared__ uint32_t xs16[16][16][4];   // [bi][rr][4 u32] f16 pairs, 4 KB
    __shared__ float    vss[16][160];      // 10 KB
    __shared__ float    lgs[8][16][12];    // logits, stride 12 (16B rows), 6 KB

    if (t < 512) {                     // stage x -> f16 LDS: 512 float4
        const int bi = t >> 5, rem = t & 31;
        const int rr = rem >> 1, hf = rem & 1;
        const float4 xv =
            *(const float4*)(x + ((size_t)(b0 + bi) * NR + rc * 16 + rr) * 8 + hf * 4);
        uint2 xp;
        xp.x = pk_f16(xv.x, xv.y);
        xp.y = pk_f16(xv.z, xv.w);
        *(uint2*)&xs16[bi][rr][hf * 2] = xp;
    }
    // stage vss: 2560 floats = 640 float4, one per thread
    ((float4*)vss)[t] = *(const float4*)(vsum + (size_t)b0 * 160 + t * 4);

    const uint32_t* wp = wf16 + (((size_t)r * NC + c) * 4 + oq) * 16;
    const uint4 w0 = *(const uint4*)(wp);
    const uint4 w1 = *(const uint4*)(wp + 4);
    const uint4 w2 = *(const uint4*)(wp + 8);
    const uint4 w3 = *(const uint4*)(wp + 12);
    __syncthreads();

    float us[8][4], own[8];
#pragma unroll
    for (int h = 0; h < 2; ++h) {
#pragma unroll
        for (int bl = 0; bl < 8; ++bl) {
            const int bi = h * 8 + bl;
            const uint4 xv = *(const uint4*)&xs16[bi][rl][0];
            float u0 = fdot2(xv.x, w0.x, 0.f);
            u0 = fdot2(xv.y, w0.y, u0);
            u0 = fdot2(xv.z, w0.z, u0);
            u0 = fdot2(xv.w, w0.w, u0);
            float u1 = fdot2(xv.x, w1.x, 0.f);
            u1 = fdot2(xv.y, w1.y, u1);
            u1 = fdot2(xv.z, w1.z, u1);
            u1 = fdot2(xv.w, w1.w, u1);
            float u2 = fdot2(xv.x, w2.x, 0.f);
            u2 = fdot2(xv.y, w2.y, u2);
            u2 = fdot2(xv.z, w2.z, u2);
            u2 = fdot2(xv.w, w2.w, u2);
            float u3 = fdot2(xv.x, w3.x, 0.f);
            u3 = fdot2(xv.y, w3.y, u3);
            u3 = fdot2(xv.z, w3.z, u3);
            u3 = fdot2(xv.w, w3.w, u3);
            us[bl][0] = u0; us[bl][1] = u1; us[bl][2] = u2; us[bl][3] = u3;
            const float4 vq = *(const float4*)&vss[bi][c * 16 + oq * 4];
            float d = u0 * vq.x;
            d = fmaf(u1, vq.y, d);
            d = fmaf(u2, vq.z, d);
            d = fmaf(u3, vq.w, d);
            d += __shfl_xor(d, 1);     // finish o-dot over 4 oq lanes
            d += __shfl_xor(d, 2);
            own[bl] = d;
            if (oq == 0) lgs[bl][rl][c] = d;
        }
        __syncthreads();
#pragma unroll
        for (int bl = 0; bl < 8; ++bl) {
            const int bi = h * 8 + bl;
            const float4 la = *(const float4*)&lgs[bl][rl][0];
            const float4 lb = *(const float4*)&lgs[bl][rl][4];
            const float2 lc = *(const float2*)&lgs[bl][rl][8];
            float m = fmaxf(fmaxf(fmaxf(la.x, la.y), fmaxf(la.z, la.w)),
                            fmaxf(fmaxf(lb.x, lb.y), fmaxf(lb.z, lb.w)));
            m = fmaxf(m, fmaxf(lc.x, lc.y));
            const float ssum =
                __expf(la.x - m) + __expf(la.y - m) + __expf(la.z - m) +
                __expf(la.w - m) + __expf(lb.x - m) + __expf(lb.y - m) +
                __expf(lb.z - m) + __expf(lb.w - m) + __expf(lc.x - m) +
                __expf(lc.y - m);
            const float wv = __expf(own[bl] - m) / ssum;
            float s0 = wv * us[bl][0], s1 = wv * us[bl][1];
            float s2 = wv * us[bl][2], s3 = wv * us[bl][3];
#pragma unroll
            for (int off = 4; off <= 32; off <<= 1) {
                s0 += __shfl_xor(s0, off); s1 += __shfl_xor(s1, off);
                s2 += __shfl_xor(s2, off); s3 += __shfl_xor(s3, off);
            }
            if ((t & 60) == 0) {       // rl == 0: 40 lanes store one uint2
                uint2 p;
                p.x = bf16_pack2(s0, s1);
                p.y = bf16_pack2(s2, s3);
                *(uint2*)(part + ((size_t)(b0 + bi) * NRC2 + rc) * 80
                          + c * 8 + oq * 2) = p;
            }
        }
        __syncthreads();               // lgs reused by next half
    }
}

// -------------------------------------------------------------------------
extern "C" void kernel_launch(void* const* d_in, const int* in_sizes, int n_in,
                              void* d_out, int out_size, void* d_ws, size_t ws_size,
                              hipStream_t stream) {
    const float* x = (const float*)d_in[0];   // [256,1152,8]
    const float* W = (const float*)d_in[1];   // [1,1152,10,8,16]
    float* out = (float*)d_out;               // [256,10,16] = [256][160]

    // ws: part1 [256][144][80]u32 = 11,796,480
    //     partA [256][72][80]u32  =  5,898,240
    //     partB [256][72][80]u32  =  5,898,240
    //     wf16  [1152][10][4][16] =  2,949,120
    //     vsum1 163,840 | vsum2 163,840      (total 26,869,760 B)
    uint8_t*  ws   = (uint8_t*)d_ws;
    uint32_t* prt1 = (uint32_t*)ws;
    uint32_t* pA   = (uint32_t*)(ws + 11796480u);
    uint32_t* pB   = (uint32_t*)(ws + 17694720u);
    uint32_t* wf16 = (uint32_t*)(ws + 23592960u);
    float*    v1   = (float*)(ws + 26542080u);
    float*    v2   = (float*)(ws + 26705920u);

    caps_s1cvt_kernel <<<2304, 320, 0, stream>>>(x, W, prt1, wf16);
    caps_reduce_kernel<<<NB, 192, 0, stream>>>(prt1, nullptr, v1, NRC, 0.1f);
    caps_pass_kernel  <<<NRC2 * 16, 640, 0, stream>>>(x, wf16, v1, pA);
    caps_reduce_kernel<<<NB, 192, 0, stream>>>(pA, v1, v2, NRC2, 1.0f);
    caps_pass_kernel  <<<NRC2 * 16, 640, 0, stream>>>(x, wf16, v2, pB);
    caps_reduce_kernel<<<NB, 192, 0, stream>>>(pB, nullptr, out, NRC2, 1.0f);
}